// Round 1
// baseline (3858.506 us; speedup 1.0000x reference)
//
#include <hip/hip_runtime.h>
#include <hip/hip_fp16.h>

#define BB 64
#define SS 1024
#define HD 256
#define GG 768   // 3*HD
#define KC 256   // dot length (input width == hidden width)

typedef _Float16 h2_t __attribute__((ext_vector_type(2)));
typedef _Float16 h8_t __attribute__((ext_vector_type(8)));

#define FDOT2(a, b, c) __builtin_amdgcn_fdot2((a), (b), (c), false)

__device__ __forceinline__ float sigm(float x) {
    return 1.0f / (1.0f + __expf(-x));
}
__device__ __forceinline__ float tanh_fast(float x) {
    float e = __expf(2.0f * fabsf(x));
    float t = 1.0f - 2.0f / (e + 1.0f);
    return copysignf(t, x);
}

// ---------------------------------------------------------------------------
// Input-side projection: xg[b,t,g] = sum_k X[b,t,k]*W[g,k] + bias[g]
// Parallel over (b, t). Weights (row g) live in each thread's registers (f16).
// X rows staged to LDS (f16), read back as broadcast b128.
// grid: (T/tb_rows, B), block: 768 threads
// ---------------------------------------------------------------------------
__global__ __launch_bounds__(GG) void proj_kernel(
    const float* __restrict__ X, int xstride,
    const float* __restrict__ W, const float* __restrict__ bias,
    float* __restrict__ xg, int t0, int T, int tb_rows)
{
    __shared__ h8_t xs[64 * 32];   // up to 64 rows x 256 halfs = 32 KB

    const int g  = threadIdx.x;    // gate row 0..767
    const int b  = blockIdx.y;
    const int tb = blockIdx.x * tb_rows;

    // weights -> registers (f16 pairs)
    h2_t w[128];
    const float2* wrow = (const float2*)(W + (size_t)g * KC);
#pragma unroll
    for (int k = 0; k < 128; k++) {
        float2 f = wrow[k];
        h2_t p; p.x = (_Float16)f.x; p.y = (_Float16)f.y;
        w[k] = p;
    }
    const float bg = bias[g];

    // stage X rows [t0+tb, t0+tb+tb_rows) as f16
    _Float16* xsh = (_Float16*)xs;
    for (int idx = g; idx < tb_rows * KC; idx += GG) {
        int tt = idx >> 8;
        int k  = idx & 255;
        xsh[tt * KC + k] =
            (_Float16)X[((size_t)b * SS + (size_t)(t0 + tb + tt)) * xstride + k];
    }
    __syncthreads();

    for (int tt = 0; tt < tb_rows; tt++) {
        const h8_t* hv = &xs[tt * 32];
        float acc = bg;
#pragma unroll
        for (int k = 0; k < 32; k++) {
            h8_t v = hv[k];   // broadcast ds_read_b128
            h2_t p0; p0.x = v[0]; p0.y = v[1];
            h2_t p1; p1.x = v[2]; p1.y = v[3];
            h2_t p2; p2.x = v[4]; p2.y = v[5];
            h2_t p3; p3.x = v[6]; p3.y = v[7];
            acc = FDOT2(w[4 * k + 0], p0, acc);
            acc = FDOT2(w[4 * k + 1], p1, acc);
            acc = FDOT2(w[4 * k + 2], p2, acc);
            acc = FDOT2(w[4 * k + 3], p3, acc);
        }
        xg[((size_t)b * T + (size_t)(tb + tt)) * GG + g] = acc;
    }
}

// ---------------------------------------------------------------------------
// Recurrence over one time chunk. One block per batch element, 768 threads.
// Thread g owns W_hh row g in registers; h kept in LDS (f16 for dots,
// f32 master copy). Waves 0-3: r gate, 4-7: z gate, 8-11: n gate + h update.
// ---------------------------------------------------------------------------
__global__ __launch_bounds__(GG) void rec_kernel(
    const float* __restrict__ xg,
    const float* __restrict__ Whh, const float* __restrict__ bhh,
    float* __restrict__ hstate,
    float* __restrict__ outA, int strideA,
    float* __restrict__ outB, int strideB,
    int t0, int T, int init)
{
    __shared__ h8_t  hs[32];    // h as 256 f16
    __shared__ float hf[HD];    // h master f32
    __shared__ float rs[HD];
    __shared__ float zs[HD];

    const int g   = threadIdx.x;
    const int b   = blockIdx.x;
    const int cls = g >> 8;     // 0=r, 1=z, 2=n (uniform per wave)
    const int i   = g & 255;

    h2_t w[128];
    const float2* wrow = (const float2*)(Whh + (size_t)g * KC);
#pragma unroll
    for (int k = 0; k < 128; k++) {
        float2 f = wrow[k];
        h2_t p; p.x = (_Float16)f.x; p.y = (_Float16)f.y;
        w[k] = p;
    }
    const float bg = bhh[g];

    if (g < HD) {
        float h0 = init ? 0.0f : hstate[(size_t)b * HD + g];
        hf[g] = h0;
        ((_Float16*)hs)[g] = (_Float16)h0;
    }
    __syncthreads();

    const float* xgp = xg + (size_t)b * T * GG + g;
    float xv = xgp[0];
    for (int tt = 0; tt < T; tt++) {
        // prefetch next step's input-side gate value (hides global latency)
        float xv_next = (tt + 1 < T) ? xgp[(size_t)(tt + 1) * GG] : 0.0f;

        float acc = bg;   // hidden-side gate pre-activation (incl. b_hh)
#pragma unroll
        for (int k = 0; k < 32; k++) {
            h8_t v = hs[k];   // broadcast ds_read_b128
            h2_t p0; p0.x = v[0]; p0.y = v[1];
            h2_t p1; p1.x = v[2]; p1.y = v[3];
            h2_t p2; p2.x = v[4]; p2.y = v[5];
            h2_t p3; p3.x = v[6]; p3.y = v[7];
            acc = FDOT2(w[4 * k + 0], p0, acc);
            acc = FDOT2(w[4 * k + 1], p1, acc);
            acc = FDOT2(w[4 * k + 2], p2, acc);
            acc = FDOT2(w[4 * k + 3], p3, acc);
        }

        if (cls == 0)      rs[i] = sigm(xv + acc);
        else if (cls == 1) zs[i] = sigm(xv + acc);
        __syncthreads();   // r,z visible; all hs reads for this step done

        if (cls == 2) {
            float r  = rs[i];
            float z  = zs[i];
            float hp = hf[i];
            float n  = tanh_fast(xv + r * acc);   // n = tanh(xn + r*hn)
            float hnew = (1.0f - z) * n + z * hp;
            hf[i] = hnew;
            ((_Float16*)hs)[i] = (_Float16)hnew;
            size_t t = (size_t)(t0 + tt);
            outA[((size_t)b * SS + t) * strideA + i] = hnew;
            if (outB) outB[((size_t)b * SS + t) * strideB + i] = hnew;
        }
        __syncthreads();   // h update visible before next step's dots
        xv = xv_next;
    }

    if (g < HD) hstate[(size_t)b * HD + g] = hf[g];
}

// ---------------------------------------------------------------------------
extern "C" void kernel_launch(void* const* d_in, const int* in_sizes, int n_in,
                              void* d_out, int out_size, void* d_ws, size_t ws_size,
                              hipStream_t stream)
{
    const float* inputs = (const float*)d_in[0];
    const float* W_ih0  = (const float*)d_in[1];
    const float* W_hh0  = (const float*)d_in[2];
    const float* b_ih0  = (const float*)d_in[3];
    const float* b_hh0  = (const float*)d_in[4];
    const float* W_ih1  = (const float*)d_in[5];
    const float* W_hh1  = (const float*)d_in[6];
    const float* b_ih1  = (const float*)d_in[7];
    const float* b_hh1  = (const float*)d_in[8];

    float* h2out = (float*)d_out;                       // [B,S,H]
    float* cat   = h2out + (size_t)BB * SS * HD;        // [B,S,2H]: [h1 | h2]

    // choose time-chunk T so xg chunk (f32) + hstate fit in workspace
    int T = SS;
    while (T > 16 &&
           (size_t)BB * T * GG * sizeof(float) + (size_t)BB * HD * sizeof(float) > ws_size)
        T >>= 1;

    float* xg     = (float*)d_ws;                       // [B,T,768] f32
    float* hstate = xg + (size_t)BB * T * GG;           // [B,256] f32

    int tbr = (T < 64) ? T : 64;
    dim3 pgrid(T / tbr, BB);
    int nc = SS / T;

    // ----- layer 0: h1 written into concat region (cols 0..255, stride 512)
    for (int c = 0; c < nc; c++) {
        int t0 = c * T;
        proj_kernel<<<pgrid, GG, 0, stream>>>(inputs, KC, W_ih0, b_ih0, xg, t0, T, tbr);
        rec_kernel<<<BB, GG, 0, stream>>>(xg, W_hh0, b_hh0, hstate,
                                          cat, 2 * HD, nullptr, 0, t0, T, c == 0);
    }
    // ----- layer 1: reads h1 from concat region; h2 written to both outputs
    for (int c = 0; c < nc; c++) {
        int t0 = c * T;
        proj_kernel<<<pgrid, GG, 0, stream>>>(cat, 2 * HD, W_ih1, b_ih1, xg, t0, T, tbr);
        rec_kernel<<<BB, GG, 0, stream>>>(xg, W_hh1, b_hh1, hstate,
                                          h2out, HD, cat + HD, 2 * HD, t0, T, c == 0);
    }
}

// Round 2
// 1881.193 us; speedup vs baseline: 2.0511x; 2.0511x over previous
//
#include <hip/hip_runtime.h>
#include <hip/hip_fp16.h>

#define BB 64
#define SS 1024
#define HD 256
#define GG 768   // 3*HD

typedef _Float16 h2_t __attribute__((ext_vector_type(2)));
typedef _Float16 h8_t __attribute__((ext_vector_type(8)));

#define FDOT2(a, b, c) __builtin_amdgcn_fdot2((a), (b), (c), false)

__device__ __forceinline__ float sigm(float x) {
    return 1.0f / (1.0f + __expf(-x));
}
__device__ __forceinline__ float tanh_fast(float x) {
    float e = __expf(2.0f * fabsf(x));
    float t = 1.0f - 2.0f / (e + 1.0f);
    return copysignf(t, x);
}

// thread g's weight row (256 f32 -> 128 packed f16 pairs in VGPRs)
__device__ __forceinline__ void load_wrow(const float* W, int g, h2_t* w) {
    const float2* wrow = (const float2*)(W + (size_t)g * 256);
#pragma unroll
    for (int k = 0; k < 128; k++) {
        float2 f = wrow[k];
        h2_t p; p.x = (_Float16)f.x; p.y = (_Float16)f.y;
        w[k] = p;
    }
}

// dot(row, v) over 256 elems; v broadcast from LDS as b128 reads
__device__ __forceinline__ float dot256(const h8_t* hv, const h2_t* w, float acc) {
#pragma unroll
    for (int k = 0; k < 32; k++) {
        h8_t v = hv[k];
        h2_t p0, p1, p2, p3;
        p0.x = v[0]; p0.y = v[1];
        p1.x = v[2]; p1.y = v[3];
        p2.x = v[4]; p2.y = v[5];
        p3.x = v[6]; p3.y = v[7];
        acc = FDOT2(w[4 * k + 0], p0, acc);
        acc = FDOT2(w[4 * k + 1], p1, acc);
        acc = FDOT2(w[4 * k + 2], p2, acc);
        acc = FDOT2(w[4 * k + 3], p3, acc);
    }
    return acc;
}

// producer/consumer flags: per-(role,batch) monotone chunk counters, 64B-padded
__device__ __forceinline__ void wait_ge(unsigned* f, unsigned v) {
    if (threadIdx.x == 0) {
        while (__hip_atomic_load(f, __ATOMIC_RELAXED, __HIP_MEMORY_SCOPE_AGENT) < v)
            __builtin_amdgcn_s_sleep(2);
        (void)__hip_atomic_load(f, __ATOMIC_ACQUIRE, __HIP_MEMORY_SCOPE_AGENT);
    }
    __syncthreads();
}
__device__ __forceinline__ void publish(unsigned* f, unsigned v) {
    __syncthreads();   // drains all waves' vmcnt (compiler emits waitcnt before barrier)
    if (threadIdx.x == 0)
        __hip_atomic_store(f, v, __ATOMIC_RELEASE, __HIP_MEMORY_SCOPE_AGENT);
}

// ---------------------------------------------------------------------------
// Persistent 4-stage pipeline: 256 blocks = 4 roles x 64 batches.
// role 0: P0  inputs -> xg0 ring          role 2: R0  xg0 -> h1 (cat)
// role 1: P1  h1(cat) -> xg1 ring         role 3: R1  xg1 -> h2 (out + cat)
// 12 waves x 170 VGPR = exactly 1 block/CU -> all 256 blocks co-resident.
// ---------------------------------------------------------------------------
__global__ __launch_bounds__(GG, 3) void gru_pipe(
    const float* __restrict__ X,
    const float* __restrict__ Wih0, const float* __restrict__ bih0,
    const float* __restrict__ Whh0, const float* __restrict__ bhh0,
    const float* __restrict__ Wih1, const float* __restrict__ bih1,
    const float* __restrict__ Whh1, const float* __restrict__ bhh1,
    float* __restrict__ h2out, float* __restrict__ cat,
    float* __restrict__ ring0, float* __restrict__ ring1,
    unsigned* __restrict__ prog, int CT, int NS, int NC)
{
    __shared__ h8_t xs[2048];                 // 32 KB staging / h-state (rec uses xs[0..31])
    __shared__ float hf[HD], rs[HD], zs[HD];

    const int role = blockIdx.x >> 6;
    const int b    = blockIdx.x & 63;
    const int g    = threadIdx.x;

    unsigned* f_p0 = prog + (0 * 64 + b) * 16;
    unsigned* f_p1 = prog + (1 * 64 + b) * 16;
    unsigned* f_r0 = prog + (2 * 64 + b) * 16;
    unsigned* f_r1 = prog + (3 * 64 + b) * 16;

    h2_t w[128];

    if (role == 0 || role == 1) {
        // ------- projection producer -------
        const float* Wp   = (role == 0) ? Wih0 : Wih1;
        const float* bp   = (role == 0) ? bih0 : bih1;
        const float* Xs   = (role == 0) ? X : cat;
        const int xstride = (role == 0) ? 256 : 512;
        float* ringo      = (role == 0) ? ring0 : ring1;
        unsigned* f_up    = (role == 0) ? nullptr : f_r0;   // P1 waits for h1 chunk
        unsigned* f_cons  = (role == 0) ? f_r0 : f_r1;      // ring reuse guard
        unsigned* f_out   = (role == 0) ? f_p0 : f_p1;

        load_wrow(Wp, g, w);
        const float bg = bp[g];
        _Float16* xsh = (_Float16*)xs;

        for (int c = 0; c < NC; c++) {
            if (f_up) wait_ge(f_up, c + 1);
            if (c >= NS) wait_ge(f_cons, c - NS + 1);
            const int t0 = c * CT;
            for (int idx = g; idx < CT * 256; idx += GG) {
                int tt = idx >> 8, k = idx & 255;
                xsh[idx] = (_Float16)Xs[((size_t)b * SS + t0 + tt) * xstride + k];
            }
            __syncthreads();
            float* ro = ringo + ((size_t)b * NS + (c % NS)) * ((size_t)CT * GG) + g;
            for (int tt = 0; tt < CT; tt++) {
                float acc = dot256(&xs[tt * 32], w, bg);
                ro[(size_t)tt * GG] = acc;
            }
            publish(f_out, c + 1);   // its syncthreads also guards LDS reuse
        }
    } else {
        // ------- recurrence -------
        const float* Wp    = (role == 2) ? Whh0 : Whh1;
        const float* bp    = (role == 2) ? bhh0 : bhh1;
        const float* ringi = (role == 2) ? ring0 : ring1;
        unsigned* f_in  = (role == 2) ? f_p0 : f_p1;
        unsigned* f_out = (role == 2) ? f_r0 : f_r1;
        float* outA   = (role == 2) ? cat : h2out;
        int   strideA = (role == 2) ? 512 : 256;
        float* outB   = (role == 2) ? nullptr : (cat + 256);   // stride 512

        load_wrow(Wp, g, w);
        const float bg = bp[g];
        const int cls = g >> 8;     // 0=r, 1=z, 2=n  (wave-uniform)
        const int i   = g & 255;

        if (g < HD) { hf[g] = 0.0f; ((_Float16*)xs)[g] = (_Float16)0.0f; }
        __syncthreads();

        for (int c = 0; c < NC; c++) {
            wait_ge(f_in, c + 1);
            const float* xgp = ringi + ((size_t)b * NS + (c % NS)) * ((size_t)CT * GG) + g;
            float xv = xgp[0];
            for (int tt = 0; tt < CT; tt++) {
                float xv_next = (tt + 1 < CT) ? xgp[(size_t)(tt + 1) * GG] : 0.0f;
                float acc = dot256(xs, w, bg);   // hidden-side gate pre-act
                if (cls == 0)      rs[i] = sigm(xv + acc);
                else if (cls == 1) zs[i] = sigm(xv + acc);
                __syncthreads();
                if (cls == 2) {
                    float r = rs[i], z = zs[i], hp = hf[i];
                    float n = tanh_fast(xv + r * acc);
                    float hnew = (1.0f - z) * n + z * hp;
                    hf[i] = hnew;
                    ((_Float16*)xs)[i] = (_Float16)hnew;
                    size_t t = (size_t)(c * CT + tt);
                    outA[((size_t)b * SS + t) * strideA + i] = hnew;
                    if (outB) outB[((size_t)b * SS + t) * 512 + i] = hnew;
                }
                __syncthreads();
                xv = xv_next;
            }
            publish(f_out, c + 1);
        }
    }
}

// ---------------------------------------------------------------------------
extern "C" void kernel_launch(void* const* d_in, const int* in_sizes, int n_in,
                              void* d_out, int out_size, void* d_ws, size_t ws_size,
                              hipStream_t stream)
{
    const float* inputs = (const float*)d_in[0];
    const float* W_ih0  = (const float*)d_in[1];
    const float* W_hh0  = (const float*)d_in[2];
    const float* b_ih0  = (const float*)d_in[3];
    const float* b_hh0  = (const float*)d_in[4];
    const float* W_ih1  = (const float*)d_in[5];
    const float* W_hh1  = (const float*)d_in[6];
    const float* b_ih1  = (const float*)d_in[7];
    const float* b_hh1  = (const float*)d_in[8];

    float* h2out = (float*)d_out;                    // [B,S,256]
    float* cat   = h2out + (size_t)BB * SS * HD;     // [B,S,512] = [h1 | h2]

    unsigned char* ws = (unsigned char*)d_ws;
    unsigned* prog = (unsigned*)ws;
    const size_t FLAG_BYTES = 4 * 64 * 16 * sizeof(unsigned);   // 64B-padded counters
    size_t avail = ws_size > FLAG_BYTES ? ws_size - FLAG_BYTES : 0;

    // pick chunk length CT and ring slots NS to fit workspace
    int CT = 64, NS = 0;
    for (;;) {
        size_t slot = (size_t)BB * CT * GG * sizeof(float);   // one slot, one ring
        size_t m = slot ? avail / (2 * slot) : 0;
        int nc = SS / CT;
        NS = (int)(m < (size_t)nc ? m : (size_t)nc);
        if (NS >= 2 || CT == 8) break;
        CT >>= 1;
    }
    if (NS < 1) NS = 1;
    int NC = SS / CT;

    float* ring0 = (float*)(ws + FLAG_BYTES);
    float* ring1 = ring0 + (size_t)BB * NS * CT * GG;

    hipMemsetAsync(prog, 0, FLAG_BYTES, stream);
    gru_pipe<<<256, GG, 0, stream>>>(inputs,
                                     W_ih0, b_ih0, W_hh0, b_hh0,
                                     W_ih1, b_ih1, W_hh1, b_hh1,
                                     h2out, cat, ring0, ring1, prog, CT, NS, NC);
}